// Round 2
// baseline (309.088 us; speedup 1.0000x reference)
//
#include <hip/hip_runtime.h>
#include <stdint.h>

typedef unsigned short u16;
typedef __attribute__((ext_vector_type(8))) short bf16x8;
typedef __attribute__((ext_vector_type(4))) float f32x4;

#define T_LEN 2048
#define D_DIM 1024
#define H_DIM 128
// sqrt(128) * log2(e)
#define SCALE_LOG2 16.32223116f

#define EXP2F(x) __builtin_amdgcn_exp2f(x)

__device__ __forceinline__ u16 f2bf(float f) {
  uint32_t u = __float_as_uint(f);
  u += 0x7FFFu + ((u >> 16) & 1u);
  return (u16)(u >> 16);
}
__device__ __forceinline__ float bf2f(u16 h) { return __uint_as_float(((uint32_t)h) << 16); }

__device__ __forceinline__ void gload16(const void* g, void* l) {
  __builtin_amdgcn_global_load_lds(
      (const __attribute__((address_space(1))) uint32_t*)(uintptr_t)g,
      (__attribute__((address_space(3))) uint32_t*)(uint32_t)(uintptr_t)l,
      16, 0, 0);
}

#define MFMA(a, b, c) __builtin_amdgcn_mfma_f32_16x16x32_bf16((a), (b), (c), 0, 0, 0)

// ---------------------------------------------------------------------------
// Kernel 0: split W matrices into bf16 hi/lo planes, transposed to wT[h][d].
// wq scaled by SCALE_LOG2 (folds softmax scale + log2(e) into q).
// ---------------------------------------------------------------------------
__global__ __launch_bounds__(256) void prep_w(
    const float* __restrict__ Wk, const float* __restrict__ Wq, const float* __restrict__ Wv,
    u16* __restrict__ wqh, u16* __restrict__ wql,
    u16* __restrict__ wkh, u16* __restrict__ wkl,
    u16* __restrict__ wvh) {
  __shared__ u16 th[3][128][16];
  __shared__ u16 tl[2][128][16];
  const int i = threadIdx.x;
  const int d0 = blockIdx.x * 16;
  const int dl = i >> 4;
  const int hb = (i & 15) * 8;
  const int d = d0 + dl;
#pragma unroll
  for (int e = 0; e < 8; ++e) {
    int h = hb + e;
    float q = Wq[d * H_DIM + h] * SCALE_LOG2;
    float k = Wk[d * H_DIM + h];
    float v = Wv[d * H_DIM + h];
    u16 qh = f2bf(q); th[0][h][dl] = qh; tl[0][h][dl] = f2bf(q - bf2f(qh));
    u16 kh = f2bf(k); th[1][h][dl] = kh; tl[1][h][dl] = f2bf(k - bf2f(kh));
    th[2][h][dl] = f2bf(v);
  }
  __syncthreads();
  const int h = i >> 1, c = i & 1;
  u16* planes[5] = {wqh, wql, wkh, wkl, wvh};
  const u16* srcs[5] = {&th[0][0][0], &tl[0][0][0], &th[1][0][0], &tl[1][0][0], &th[2][0][0]};
#pragma unroll
  for (int p = 0; p < 5; ++p) {
    bf16x8 v8 = *(const bf16x8*)(srcs[p] + h * 16 + c * 8);
    *(bf16x8*)(planes[p] + h * 1024 + d0 + c * 8) = v8;
  }
}

// ---------------------------------------------------------------------------
// Kernel 1: q = att@Wq'+bq' (split hi/lo), k = att@Wk+bk (split hi/lo),
//           v = x@Wv+bv (bf16, stored transposed vT[b][h][t]).
// 64 rows per block, 4 waves; wave owns n-tiles {2w, 2w+1} over all rows.
// ---------------------------------------------------------------------------
__global__ __launch_bounds__(256) void qkv_proj(
    const float* __restrict__ att, const float* __restrict__ x,
    const u16* __restrict__ wqh, const u16* __restrict__ wql,
    const u16* __restrict__ wkh, const u16* __restrict__ wkl,
    const u16* __restrict__ wvh,
    const float* __restrict__ bq, const float* __restrict__ bk, const float* __restrict__ bv,
    u16* __restrict__ qhp, u16* __restrict__ qlp,
    u16* __restrict__ khp, u16* __restrict__ klp,
    u16* __restrict__ vtp) {
  __shared__ __attribute__((aligned(128))) char lds[52 * 1024];
  char* aAh = lds;             // [64 rows][64B]  att hi
  char* aAl = lds + 4096;      // att lo
  char* aXh = lds + 8192;      // x hi
  char* wt  = lds + 12288;     // 5 planes x 8KB, each [128 h][64B]
  char* vbuf = lds + 12288;    // epilogue reuse: [128 h][128B]

  const int tid = threadIdx.x;
  const int wid = tid >> 6;
  const int ln = tid & 63;
  const int g = ln >> 4;
  const int cl = ln & 15;
  const int t0g = blockIdx.x * 64;

  const f32x4 fz = {0.f, 0.f, 0.f, 0.f};
  f32x4 accq[2][4], acck[2][4], accv[2][4];
#pragma unroll
  for (int a = 0; a < 2; ++a)
#pragma unroll
    for (int s = 0; s < 4; ++s) { accq[a][s] = fz; acck[a][s] = fz; accv[a][s] = fz; }

  const int arow = tid >> 2;   // 0..63
  const int ac = tid & 3;      // 16B chunk within 64B row
  const float* attp = att + (size_t)(t0g + arow) * D_DIM + ac * 8;
  const float* xp   = x   + (size_t)(t0g + arow) * D_DIM + ac * 8;
  char* aw = aAh + arow * 64 + ((ac ^ ((arow >> 1) & 3)) * 16);

  for (int ks = 0; ks < 32; ++ks) {
    __syncthreads();
    // --- stage A tiles (fp32 -> bf16 hi/lo), swizzled chunk ---
    {
      f32x4 f0 = *(const f32x4*)(attp + ks * 32);
      f32x4 f1 = *(const f32x4*)(attp + ks * 32 + 4);
      f32x4 g0 = *(const f32x4*)(xp + ks * 32);
      f32x4 g1 = *(const f32x4*)(xp + ks * 32 + 4);
      bf16x8 vh, vl, vx;
#pragma unroll
      for (int e = 0; e < 4; ++e) {
        u16 h0 = f2bf(f0[e]); vh[e] = (short)h0; vl[e] = (short)f2bf(f0[e] - bf2f(h0));
        u16 h1 = f2bf(f1[e]); vh[e + 4] = (short)h1; vl[e + 4] = (short)f2bf(f1[e] - bf2f(h1));
        vx[e] = (short)f2bf(g0[e]); vx[e + 4] = (short)f2bf(g1[e]);
      }
      *(bf16x8*)aw = vh;
      *(bf16x8*)(aw + 4096) = vl;
      *(bf16x8*)(aw + 8192) = vx;
    }
    // --- stage W tiles: 5 planes x 8 segs of 1KB via global_load_lds ---
#pragma unroll
    for (int j = 0; j < 10; ++j) {
      int seg = wid * 10 + j;
      int p = seg >> 3;
      int s = seg & 7;
      int db = s * 1024 + ln * 16;
      int row = db >> 6;
      int c = (db >> 4) & 3;
      int cs = c ^ ((row >> 1) & 3);
      const u16* wp = (p == 0) ? wqh : (p == 1) ? wql : (p == 2) ? wkh : (p == 3) ? wkl : wvh;
      gload16(wp + row * 1024 + ks * 32 + cs * 8, wt + p * 8192 + s * 1024);
    }
    __syncthreads();
    // --- compute ---
    bf16x8 ah[4], al[4], xh[4];
#pragma unroll
    for (int s = 0; s < 4; ++s) {
      int row = s * 16 + cl;
      int byte = row * 64 + ((g ^ ((row >> 1) & 3)) * 16);
      ah[s] = *(const bf16x8*)(aAh + byte);
      al[s] = *(const bf16x8*)(aAl + byte);
      xh[s] = *(const bf16x8*)(aXh + byte);
    }
#pragma unroll
    for (int lnt = 0; lnt < 2; ++lnt) {
      int hrow = (2 * wid + lnt) * 16 + cl;
      int wb = hrow * 64 + ((g ^ ((hrow >> 1) & 3)) * 16);
      bf16x8 bqh_ = *(const bf16x8*)(wt + 0 * 8192 + wb);
      bf16x8 bql_ = *(const bf16x8*)(wt + 1 * 8192 + wb);
      bf16x8 bkh_ = *(const bf16x8*)(wt + 2 * 8192 + wb);
      bf16x8 bkl_ = *(const bf16x8*)(wt + 3 * 8192 + wb);
      bf16x8 bvh_ = *(const bf16x8*)(wt + 4 * 8192 + wb);
#pragma unroll
      for (int s = 0; s < 4; ++s) {
        accq[lnt][s] = MFMA(ah[s], bqh_, accq[lnt][s]);
        accq[lnt][s] = MFMA(al[s], bqh_, accq[lnt][s]);
        accq[lnt][s] = MFMA(ah[s], bql_, accq[lnt][s]);
        acck[lnt][s] = MFMA(ah[s], bkh_, acck[lnt][s]);
        acck[lnt][s] = MFMA(al[s], bkh_, acck[lnt][s]);
        acck[lnt][s] = MFMA(ah[s], bkl_, acck[lnt][s]);
        accv[lnt][s] = MFMA(xh[s], bvh_, accv[lnt][s]);
      }
    }
  }
  __syncthreads();
  // --- epilogue: bias, split q/k, write planes; v -> LDS transpose buffer ---
#pragma unroll
  for (int lnt = 0; lnt < 2; ++lnt) {
    int h = (2 * wid + lnt) * 16 + cl;
    float bqv = bq[h] * SCALE_LOG2, bkv = bk[h], bvv = bv[h];
#pragma unroll
    for (int s = 0; s < 4; ++s) {
#pragma unroll
      for (int r = 0; r < 4; ++r) {
        int t = s * 16 + g * 4 + r;
        size_t idx = (size_t)(t0g + t) * H_DIM + h;
        float qv = accq[lnt][s][r] + bqv;
        u16 qh_ = f2bf(qv);
        qhp[idx] = qh_;
        qlp[idx] = f2bf(qv - bf2f(qh_));
        float kv = acck[lnt][s][r] + bkv;
        u16 kh_ = f2bf(kv);
        khp[idx] = kh_;
        klp[idx] = f2bf(kv - bf2f(kh_));
        float vv = accv[lnt][s][r] + bvv;
        int c3 = t >> 3;
        int byte = h * 128 + ((c3 ^ (h & 7)) * 16) + (t & 7) * 2;
        *(u16*)(vbuf + byte) = f2bf(vv);
      }
    }
  }
  __syncthreads();
  // --- vT coalesced writeout ---
  {
    int h = tid >> 1, half = tid & 1;
    int b_ = t0g >> 11;
    int tb = t0g & 2047;
    u16* dst = vtp + ((size_t)(b_ * H_DIM + h)) * T_LEN + tb + half * 32;
#pragma unroll
    for (int c2 = 0; c2 < 4; ++c2) {
      int c3 = half * 4 + c2;
      bf16x8 v8 = *(const bf16x8*)(vbuf + h * 128 + ((c3 ^ (h & 7)) * 16));
      *(bf16x8*)(dst + c2 * 8) = v8;
    }
  }
}

// ---------------------------------------------------------------------------
// Kernel 2: flash attention. Block = 64 q-rows (4 waves x 16), KV tile 64.
// Scores via split bf16 (qhi*khi + qlo*khi + qhi*klo); online softmax in exp2.
// ---------------------------------------------------------------------------
__global__ __launch_bounds__(256) void attn(
    const u16* __restrict__ qhp, const u16* __restrict__ qlp,
    const u16* __restrict__ khp, const u16* __restrict__ klp,
    const u16* __restrict__ vtp,
    float* __restrict__ out) {
  __shared__ __attribute__((aligned(128))) char lds[56 * 1024];
  char* kH = lds;              // [64][256B]
  char* kL = lds + 16384;
  char* vT = lds + 32768;      // [128][128B]
  char* pB = lds + 49152;      // per-wave 2KB: [16][128B]

  const int tid = threadIdx.x;
  const int wid = tid >> 6;
  const int ln = tid & 63;
  const int g = ln >> 4;
  const int cl = ln & 15;
  const int b_ = blockIdx.y;
  const int t0 = blockIdx.x * 64;
  char* pW = pB + wid * 2048;

  bf16x8 qh_f[4], ql_f[4];
  {
    size_t qrow = (size_t)(b_ * T_LEN + t0 + wid * 16 + cl) * H_DIM;
#pragma unroll
    for (int kc = 0; kc < 4; ++kc) {
      qh_f[kc] = *(const bf16x8*)(qhp + qrow + kc * 32 + g * 8);
      ql_f[kc] = *(const bf16x8*)(qlp + qrow + kc * 32 + g * 8);
    }
  }
  const f32x4 fz = {0.f, 0.f, 0.f, 0.f};
  float m_[4] = {-1e30f, -1e30f, -1e30f, -1e30f};
  float l_[4] = {0.f, 0.f, 0.f, 0.f};
  f32x4 o_[8];
#pragma unroll
  for (int ht = 0; ht < 8; ++ht) o_[ht] = fz;

  for (int kv = 0; kv < 32; ++kv) {
    const int tk = kv * 64;
    __syncthreads();
    // stage K hi/lo + vT, source pre-swizzled so linear LDS dest == swizzled
#pragma unroll
    for (int j = 0; j < 4; ++j) {
      int s = wid * 4 + j;
      int db = s * 1024 + ln * 16;
      int row = db >> 8;
      int c16 = (db >> 4) & 15;
      int cs = c16 ^ (row & 7);
      size_t gidx = (size_t)(b_ * T_LEN + tk + row) * H_DIM + cs * 8;
      gload16(khp + gidx, kH + s * 1024);
      gload16(klp + gidx, kL + s * 1024);
      int vrow = db >> 7;
      int c3 = (db >> 4) & 7;
      int vcs = c3 ^ (vrow & 7);
      size_t vidx = (size_t)(b_ * H_DIM + vrow) * T_LEN + tk + vcs * 8;
      gload16(vtp + vidx, vT + s * 1024);
    }
    __syncthreads();
    // --- QK^T (split) ---
    f32x4 sc[4];
#pragma unroll
    for (int nt = 0; nt < 4; ++nt) sc[nt] = fz;
#pragma unroll
    for (int kc = 0; kc < 4; ++kc) {
#pragma unroll
      for (int nt = 0; nt < 4; ++nt) {
        int row = nt * 16 + cl;
        int byte = row * 256 + (((kc * 4 + g) ^ (row & 7)) * 16);
        bf16x8 bh = *(const bf16x8*)(kH + byte);
        bf16x8 bl = *(const bf16x8*)(kL + byte);
        sc[nt] = MFMA(qh_f[kc], bh, sc[nt]);
        sc[nt] = MFMA(ql_f[kc], bh, sc[nt]);
        sc[nt] = MFMA(qh_f[kc], bl, sc[nt]);
      }
    }
    // --- online softmax (exp2 domain) ---
    float sfv[4];
#pragma unroll
    for (int r = 0; r < 4; ++r) {
      float pm = fmaxf(fmaxf(sc[0][r], sc[1][r]), fmaxf(sc[2][r], sc[3][r]));
#pragma unroll
      for (int d = 1; d < 16; d <<= 1) pm = fmaxf(pm, __shfl_xor(pm, d));
      float mn = fmaxf(m_[r], pm);
      float sf = EXP2F(m_[r] - mn);
      m_[r] = mn; sfv[r] = sf;
      float ps = 0.f;
      int prow = g * 4 + r;
#pragma unroll
      for (int nt = 0; nt < 4; ++nt) {
        float p = EXP2F(sc[nt][r] - mn);
        ps += p;
        int c3 = nt * 2 + (cl >> 3);
        int byte = prow * 128 + ((c3 ^ (prow & 7)) * 16) + (cl & 7) * 2;
        *(u16*)(pW + byte) = f2bf(p);
      }
#pragma unroll
      for (int d = 1; d < 16; d <<= 1) ps += __shfl_xor(ps, d);
      l_[r] = l_[r] * sf + ps;
    }
#pragma unroll
    for (int ht = 0; ht < 8; ++ht) {
      o_[ht][0] *= sfv[0]; o_[ht][1] *= sfv[1]; o_[ht][2] *= sfv[2]; o_[ht][3] *= sfv[3];
    }
    // --- PV ---
#pragma unroll
    for (int kc2 = 0; kc2 < 2; ++kc2) {
      int pbyte = cl * 128 + (((kc2 * 4 + g) ^ (cl & 7)) * 16);
      bf16x8 ap = *(const bf16x8*)(pW + pbyte);
#pragma unroll
      for (int ht = 0; ht < 8; ++ht) {
        int vrow = ht * 16 + cl;
        int vbyte = vrow * 128 + (((kc2 * 4 + g) ^ (vrow & 7)) * 16);
        bf16x8 bv_ = *(const bf16x8*)(vT + vbyte);
        o_[ht] = MFMA(ap, bv_, o_[ht]);
      }
    }
  }
  // --- epilogue ---
  float inv[4];
#pragma unroll
  for (int r = 0; r < 4; ++r) inv[r] = 1.f / l_[r];
  size_t obase = (size_t)(b_ * T_LEN + t0 + wid * 16) * H_DIM;
#pragma unroll
  for (int r = 0; r < 4; ++r) {
#pragma unroll
    for (int ht = 0; ht < 8; ++ht) {
      out[obase + (size_t)(g * 4 + r) * H_DIM + ht * 16 + cl] = o_[ht][r] * inv[r];
    }
  }
}

// ---------------------------------------------------------------------------
extern "C" void kernel_launch(void* const* d_in, const int* in_sizes, int n_in,
                              void* d_out, int out_size, void* d_ws, size_t ws_size,
                              hipStream_t stream) {
  const float* x   = (const float*)d_in[0];
  const float* att = (const float*)d_in[1];
  const float* Wk  = (const float*)d_in[2];
  const float* bk  = (const float*)d_in[3];
  const float* Wq  = (const float*)d_in[4];
  const float* bq  = (const float*)d_in[5];
  const float* Wv  = (const float*)d_in[6];
  const float* bv  = (const float*)d_in[7];
  float* out = (float*)d_out;
  char* ws = (char*)d_ws;

  u16* wqh = (u16*)(ws);
  u16* wql = (u16*)(ws + 256 * 1024);
  u16* wkh = (u16*)(ws + 512 * 1024);
  u16* wkl = (u16*)(ws + 768 * 1024);
  u16* wvh = (u16*)(ws + 1024 * 1024);
  u16* qhp = (u16*)(ws + (size_t)2 * 1024 * 1024);
  u16* qlp = (u16*)(ws + (size_t)6 * 1024 * 1024);
  u16* khp = (u16*)(ws + (size_t)10 * 1024 * 1024);
  u16* klp = (u16*)(ws + (size_t)14 * 1024 * 1024);
  u16* vtp = (u16*)(ws + (size_t)18 * 1024 * 1024);

  prep_w<<<64, 256, 0, stream>>>(Wk, Wq, Wv, wqh, wql, wkh, wkl, wvh);
  qkv_proj<<<256, 256, 0, stream>>>(att, x, wqh, wql, wkh, wkl, wvh,
                                    bq, bk, bv, qhp, qlp, khp, klp, vtp);
  attn<<<dim3(32, 8), 256, 0, stream>>>(qhp, qlp, khp, klp, vtp, out);
}

// Round 3
// 265.177 us; speedup vs baseline: 1.1656x; 1.1656x over previous
//
#include <hip/hip_runtime.h>
#include <stdint.h>

typedef unsigned short u16;
typedef __attribute__((ext_vector_type(8))) short bf16x8;
typedef __attribute__((ext_vector_type(4))) float f32x4;

#define T_LEN 2048
#define D_DIM 1024
#define H_DIM 128
// sqrt(128) * log2(e)
#define SCALE_LOG2 16.32223116f

#define EXP2F(x) __builtin_amdgcn_exp2f(x)

__device__ __forceinline__ u16 f2bf(float f) {
  uint32_t u = __float_as_uint(f);
  u += 0x7FFFu + ((u >> 16) & 1u);
  return (u16)(u >> 16);
}
__device__ __forceinline__ float bf2f(u16 h) { return __uint_as_float(((uint32_t)h) << 16); }

__device__ __forceinline__ void gload16(const void* g, void* l) {
  __builtin_amdgcn_global_load_lds(
      (const __attribute__((address_space(1))) uint32_t*)(uintptr_t)g,
      (__attribute__((address_space(3))) uint32_t*)(uint32_t)(uintptr_t)l,
      16, 0, 0);
}

#define VMCNT0() asm volatile("s_waitcnt vmcnt(0)" ::: "memory")
#define VMLG0() asm volatile("s_waitcnt vmcnt(0) lgkmcnt(0)" ::: "memory")
#define BAR() __builtin_amdgcn_s_barrier()

#define MFMA(a, b, c) __builtin_amdgcn_mfma_f32_16x16x32_bf16((a), (b), (c), 0, 0, 0)

// ---------------------------------------------------------------------------
// Kernel 0: split W matrices into bf16 hi/lo planes, transposed to wT[h][d].
// ---------------------------------------------------------------------------
__global__ __launch_bounds__(256) void prep_w(
    const float* __restrict__ Wk, const float* __restrict__ Wq, const float* __restrict__ Wv,
    u16* __restrict__ wqh, u16* __restrict__ wql,
    u16* __restrict__ wkh, u16* __restrict__ wkl,
    u16* __restrict__ wvh) {
  __shared__ u16 th[3][128][16];
  __shared__ u16 tl[2][128][16];
  const int i = threadIdx.x;
  const int d0 = blockIdx.x * 16;
  const int dl = i >> 4;
  const int hb = (i & 15) * 8;
  const int d = d0 + dl;
#pragma unroll
  for (int e = 0; e < 8; ++e) {
    int h = hb + e;
    float q = Wq[d * H_DIM + h] * SCALE_LOG2;
    float k = Wk[d * H_DIM + h];
    float v = Wv[d * H_DIM + h];
    u16 qh = f2bf(q); th[0][h][dl] = qh; tl[0][h][dl] = f2bf(q - bf2f(qh));
    u16 kh = f2bf(k); th[1][h][dl] = kh; tl[1][h][dl] = f2bf(k - bf2f(kh));
    th[2][h][dl] = f2bf(v);
  }
  __syncthreads();
  const int h = i >> 1, c = i & 1;
  u16* planes[5] = {wqh, wql, wkh, wkl, wvh};
  const u16* srcs[5] = {&th[0][0][0], &tl[0][0][0], &th[1][0][0], &tl[1][0][0], &th[2][0][0]};
#pragma unroll
  for (int p = 0; p < 5; ++p) {
    bf16x8 v8 = *(const bf16x8*)(srcs[p] + h * 16 + c * 8);
    *(bf16x8*)(planes[p] + h * 1024 + d0 + c * 8) = v8;
  }
}

// ---------------------------------------------------------------------------
// Kernel 1: QKV projection, 2-phase prefetch pipeline (double-buffered LDS).
// ---------------------------------------------------------------------------
#define QBUF 53248  // 52 KB per buffer: A(12K) + W(40K)

__global__ __launch_bounds__(256) void qkv_proj(
    const float* __restrict__ att, const float* __restrict__ x,
    const u16* __restrict__ wqh, const u16* __restrict__ wql,
    const u16* __restrict__ wkh, const u16* __restrict__ wkl,
    const u16* __restrict__ wvh,
    const float* __restrict__ bq, const float* __restrict__ bk, const float* __restrict__ bv,
    u16* __restrict__ qhp, u16* __restrict__ qlp,
    u16* __restrict__ khp, u16* __restrict__ klp,
    u16* __restrict__ vtp) {
  __shared__ __attribute__((aligned(128))) char lds[104 * 1024];

  const int tid = threadIdx.x;
  const int wid = tid >> 6;
  const int ln = tid & 63;
  const int g = ln >> 4;
  const int cl = ln & 15;
  const int t0g = blockIdx.x * 64;

  const f32x4 fz = {0.f, 0.f, 0.f, 0.f};
  f32x4 accq[2][4], acck[2][4], accv[2][4];
#pragma unroll
  for (int a = 0; a < 2; ++a)
#pragma unroll
    for (int s = 0; s < 4; ++s) { accq[a][s] = fz; acck[a][s] = fz; accv[a][s] = fz; }

  const int arow = tid >> 2;   // 0..63
  const int ac = tid & 3;      // 16B chunk within 64B row
  const float* attp = att + (size_t)(t0g + arow) * D_DIM + ac * 8;
  const float* xp   = x   + (size_t)(t0g + arow) * D_DIM + ac * 8;
  const int aw_off = arow * 64 + ((ac ^ ((arow >> 1) & 3)) * 16);

  // stage W planes for K-step ks into buffer b (global_load_lds, pre-swizzled src)
  auto STAGE_W = [&](int b, int ks) {
    char* wt = lds + b * QBUF + 12288;
#pragma unroll
    for (int j = 0; j < 10; ++j) {
      int seg = wid * 10 + j;
      int p = seg >> 3;
      int s = seg & 7;
      int db = s * 1024 + ln * 16;
      int row = db >> 6;
      int c = (db >> 4) & 3;
      int cs = c ^ ((row >> 1) & 3);
      const u16* wp = (p == 0) ? wqh : (p == 1) ? wql : (p == 2) ? wkh : (p == 3) ? wkl : wvh;
      gload16(wp + row * 1024 + ks * 32 + cs * 8, wt + p * 8192 + s * 1024);
    }
  };
  // convert prefetched fp32 A regs to bf16 hi/lo and write into buffer b
  auto CWRITE_A = [&](int b, f32x4 f0, f32x4 f1, f32x4 g0, f32x4 g1) {
    bf16x8 vh, vl, vx;
#pragma unroll
    for (int e = 0; e < 4; ++e) {
      u16 h0 = f2bf(f0[e]); vh[e] = (short)h0; vl[e] = (short)f2bf(f0[e] - bf2f(h0));
      u16 h1 = f2bf(f1[e]); vh[e + 4] = (short)h1; vl[e + 4] = (short)f2bf(f1[e] - bf2f(h1));
      vx[e] = (short)f2bf(g0[e]); vx[e + 4] = (short)f2bf(g1[e]);
    }
    char* dst = lds + b * QBUF + aw_off;
    *(bf16x8*)dst = vh;
    *(bf16x8*)(dst + 4096) = vl;
    *(bf16x8*)(dst + 8192) = vx;
  };

  // --- prologue: fill buffer 0 for ks=0 ---
  {
    f32x4 f0 = *(const f32x4*)(attp);
    f32x4 f1 = *(const f32x4*)(attp + 4);
    f32x4 g0 = *(const f32x4*)(xp);
    f32x4 g1 = *(const f32x4*)(xp + 4);
    STAGE_W(0, 0);
    CWRITE_A(0, f0, f1, g0, g1);
  }
  VMLG0();
  BAR();

  int cur = 0;
  for (int ks = 0; ks < 32; ++ks) {
    // --- issue next-tile loads early ---
    f32x4 pf0, pf1, pg0, pg1;
    if (ks < 31) {
      pf0 = *(const f32x4*)(attp + (ks + 1) * 32);
      pf1 = *(const f32x4*)(attp + (ks + 1) * 32 + 4);
      pg0 = *(const f32x4*)(xp + (ks + 1) * 32);
      pg1 = *(const f32x4*)(xp + (ks + 1) * 32 + 4);
      STAGE_W(cur ^ 1, ks + 1);
    }
    // --- compute on current buffer ---
    char* base = lds + cur * QBUF;
    char* aAh = base;
    char* aAl = base + 4096;
    char* aXh = base + 8192;
    char* wt  = base + 12288;
    bf16x8 ah[4], al[4], xh[4];
#pragma unroll
    for (int s = 0; s < 4; ++s) {
      int row = s * 16 + cl;
      int byte = row * 64 + ((g ^ ((row >> 1) & 3)) * 16);
      ah[s] = *(const bf16x8*)(aAh + byte);
      al[s] = *(const bf16x8*)(aAl + byte);
      xh[s] = *(const bf16x8*)(aXh + byte);
    }
#pragma unroll
    for (int lnt = 0; lnt < 2; ++lnt) {
      int hrow = (2 * wid + lnt) * 16 + cl;
      int wb = hrow * 64 + ((g ^ ((hrow >> 1) & 3)) * 16);
      bf16x8 bqh_ = *(const bf16x8*)(wt + 0 * 8192 + wb);
      bf16x8 bql_ = *(const bf16x8*)(wt + 1 * 8192 + wb);
      bf16x8 bkh_ = *(const bf16x8*)(wt + 2 * 8192 + wb);
      bf16x8 bkl_ = *(const bf16x8*)(wt + 3 * 8192 + wb);
      bf16x8 bvh_ = *(const bf16x8*)(wt + 4 * 8192 + wb);
#pragma unroll
      for (int s = 0; s < 4; ++s) {
        accq[lnt][s] = MFMA(ah[s], bqh_, accq[lnt][s]);
        accq[lnt][s] = MFMA(al[s], bqh_, accq[lnt][s]);
        accq[lnt][s] = MFMA(ah[s], bql_, accq[lnt][s]);
        acck[lnt][s] = MFMA(ah[s], bkh_, acck[lnt][s]);
        acck[lnt][s] = MFMA(al[s], bkh_, acck[lnt][s]);
        acck[lnt][s] = MFMA(ah[s], bkl_, acck[lnt][s]);
        accv[lnt][s] = MFMA(xh[s], bvh_, accv[lnt][s]);
      }
    }
    // --- write prefetched A into next buffer (loads had compute time to land) ---
    if (ks < 31) CWRITE_A(cur ^ 1, pf0, pf1, pg0, pg1);
    VMLG0();
    BAR();
    cur ^= 1;
  }

  // --- epilogue: bias, split q/k, write planes; v -> LDS transpose buffer ---
  char* vbuf = lds;  // 16 KB, all compute done (post final barrier)
#pragma unroll
  for (int lnt = 0; lnt < 2; ++lnt) {
    int h = (2 * wid + lnt) * 16 + cl;
    float bqv = bq[h] * SCALE_LOG2, bkv = bk[h], bvv = bv[h];
#pragma unroll
    for (int s = 0; s < 4; ++s) {
#pragma unroll
      for (int r = 0; r < 4; ++r) {
        int t = s * 16 + g * 4 + r;
        size_t idx = (size_t)(t0g + t) * H_DIM + h;
        float qv = accq[lnt][s][r] + bqv;
        u16 qh_ = f2bf(qv);
        qhp[idx] = qh_;
        qlp[idx] = f2bf(qv - bf2f(qh_));
        float kv = acck[lnt][s][r] + bkv;
        u16 kh_ = f2bf(kv);
        khp[idx] = kh_;
        klp[idx] = f2bf(kv - bf2f(kh_));
        float vv = accv[lnt][s][r] + bvv;
        int c3 = t >> 3;
        int byte = h * 128 + ((c3 ^ (h & 7)) * 16) + (t & 7) * 2;
        *(u16*)(vbuf + byte) = f2bf(vv);
      }
    }
  }
  __syncthreads();
  // --- vT coalesced writeout ---
  {
    int h = tid >> 1, half = tid & 1;
    int b_ = t0g >> 11;
    int tb = t0g & 2047;
    u16* dst = vtp + ((size_t)(b_ * H_DIM + h)) * T_LEN + tb + half * 32;
#pragma unroll
    for (int c2 = 0; c2 < 4; ++c2) {
      int c3 = half * 4 + c2;
      bf16x8 v8 = *(const bf16x8*)(vbuf + h * 128 + ((c3 ^ (h & 7)) * 16));
      *(bf16x8*)(dst + c2 * 8) = v8;
    }
  }
}

// ---------------------------------------------------------------------------
// Kernel 2: flash attention, 2-phase prefetch pipeline (double-buffered KV).
// 1-D grid, batch = bid & 7 so each XCD's L2 holds one batch's KV.
// ---------------------------------------------------------------------------
#define ABUF 49152  // 48 KB per buffer: kH(16K) + kL(16K) + vT(16K)

__global__ __launch_bounds__(256) void attn(
    const u16* __restrict__ qhp, const u16* __restrict__ qlp,
    const u16* __restrict__ khp, const u16* __restrict__ klp,
    const u16* __restrict__ vtp,
    float* __restrict__ out) {
  __shared__ __attribute__((aligned(128))) char lds[104 * 1024];
  char* pB = lds + 96 * 1024;  // per-wave 2KB: [16][128B]

  const int tid = threadIdx.x;
  const int wid = tid >> 6;
  const int ln = tid & 63;
  const int g = ln >> 4;
  const int cl = ln & 15;
  const int bid = blockIdx.x;
  const int b_ = bid & 7;        // batch -> XCD
  const int t0 = (bid >> 3) * 64;
  char* pW = pB + wid * 2048;

  auto STAGE = [&](int b, int tk) {
    char* kH = lds + b * ABUF;
    char* kL = kH + 16384;
    char* vT = kH + 32768;
#pragma unroll
    for (int j = 0; j < 4; ++j) {
      int s = wid * 4 + j;
      int db = s * 1024 + ln * 16;
      int row = db >> 8;
      int c16 = (db >> 4) & 15;
      int cs = c16 ^ (row & 7);
      size_t gidx = (size_t)(b_ * T_LEN + tk + row) * H_DIM + cs * 8;
      gload16(khp + gidx, kH + s * 1024);
      gload16(klp + gidx, kL + s * 1024);
      int vrow = db >> 7;
      int c3 = (db >> 4) & 7;
      int vcs = c3 ^ (vrow & 7);
      size_t vidx = (size_t)(b_ * H_DIM + vrow) * T_LEN + tk + vcs * 8;
      gload16(vtp + vidx, vT + s * 1024);
    }
  };

  bf16x8 qh_f[4], ql_f[4];
  {
    size_t qrow = (size_t)(b_ * T_LEN + t0 + wid * 16 + cl) * H_DIM;
#pragma unroll
    for (int kc = 0; kc < 4; ++kc) {
      qh_f[kc] = *(const bf16x8*)(qhp + qrow + kc * 32 + g * 8);
      ql_f[kc] = *(const bf16x8*)(qlp + qrow + kc * 32 + g * 8);
    }
  }
  const f32x4 fz = {0.f, 0.f, 0.f, 0.f};
  float m_[4] = {-1e30f, -1e30f, -1e30f, -1e30f};
  float l_[4] = {0.f, 0.f, 0.f, 0.f};
  f32x4 o_[8];
#pragma unroll
  for (int ht = 0; ht < 8; ++ht) o_[ht] = fz;

  // --- prologue ---
  STAGE(0, 0);
  VMCNT0();
  BAR();

  int cur = 0;
  for (int kv = 0; kv < 32; ++kv) {
    // --- issue next KV tile loads early ---
    if (kv < 31) STAGE(cur ^ 1, (kv + 1) * 64);

    char* kH = lds + cur * ABUF;
    char* kL = kH + 16384;
    char* vT = kH + 32768;
    // --- QK^T (split) ---
    f32x4 sc[4];
#pragma unroll
    for (int nt = 0; nt < 4; ++nt) sc[nt] = fz;
#pragma unroll
    for (int kc = 0; kc < 4; ++kc) {
#pragma unroll
      for (int nt = 0; nt < 4; ++nt) {
        int row = nt * 16 + cl;
        int byte = row * 256 + (((kc * 4 + g) ^ (row & 7)) * 16);
        bf16x8 bh = *(const bf16x8*)(kH + byte);
        bf16x8 bl = *(const bf16x8*)(kL + byte);
        sc[nt] = MFMA(qh_f[kc], bh, sc[nt]);
        sc[nt] = MFMA(ql_f[kc], bh, sc[nt]);
        sc[nt] = MFMA(qh_f[kc], bl, sc[nt]);
      }
    }
    // --- online softmax (exp2 domain) ---
    float sfv[4];
#pragma unroll
    for (int r = 0; r < 4; ++r) {
      float pm = fmaxf(fmaxf(sc[0][r], sc[1][r]), fmaxf(sc[2][r], sc[3][r]));
#pragma unroll
      for (int d = 1; d < 16; d <<= 1) pm = fmaxf(pm, __shfl_xor(pm, d));
      float mn = fmaxf(m_[r], pm);
      float sf = EXP2F(m_[r] - mn);
      m_[r] = mn; sfv[r] = sf;
      float ps = 0.f;
      int prow = g * 4 + r;
#pragma unroll
      for (int nt = 0; nt < 4; ++nt) {
        float p = EXP2F(sc[nt][r] - mn);
        ps += p;
        int c3 = nt * 2 + (cl >> 3);
        int byte = prow * 128 + ((c3 ^ (prow & 7)) * 16) + (cl & 7) * 2;
        *(u16*)(pW + byte) = f2bf(p);
      }
#pragma unroll
      for (int d = 1; d < 16; d <<= 1) ps += __shfl_xor(ps, d);
      l_[r] = l_[r] * sf + ps;
    }
#pragma unroll
    for (int ht = 0; ht < 8; ++ht) {
      o_[ht][0] *= sfv[0]; o_[ht][1] *= sfv[1]; o_[ht][2] *= sfv[2]; o_[ht][3] *= sfv[3];
    }
    // --- PV ---
#pragma unroll
    for (int kc2 = 0; kc2 < 2; ++kc2) {
      int pbyte = cl * 128 + (((kc2 * 4 + g) ^ (cl & 7)) * 16);
      bf16x8 ap = *(const bf16x8*)(pW + pbyte);
#pragma unroll
      for (int ht = 0; ht < 8; ++ht) {
        int vrow = ht * 16 + cl;
        int vbyte = vrow * 128 + (((kc2 * 4 + g) ^ (vrow & 7)) * 16);
        bf16x8 bv_ = *(const bf16x8*)(vT + vbyte);
        o_[ht] = MFMA(ap, bv_, o_[ht]);
      }
    }
    // --- next tile ready gate: drain prefetch, single barrier per tile ---
    VMCNT0();
    BAR();
    cur ^= 1;
  }
  // --- epilogue ---
  float inv[4];
#pragma unroll
  for (int r = 0; r < 4; ++r) inv[r] = 1.f / l_[r];
  size_t obase = (size_t)(b_ * T_LEN + t0 + wid * 16) * H_DIM;
#pragma unroll
  for (int r = 0; r < 4; ++r) {
#pragma unroll
    for (int ht = 0; ht < 8; ++ht) {
      out[obase + (size_t)(g * 4 + r) * H_DIM + ht * 16 + cl] = o_[ht][r] * inv[r];
    }
  }
}

// ---------------------------------------------------------------------------
extern "C" void kernel_launch(void* const* d_in, const int* in_sizes, int n_in,
                              void* d_out, int out_size, void* d_ws, size_t ws_size,
                              hipStream_t stream) {
  const float* x   = (const float*)d_in[0];
  const float* att = (const float*)d_in[1];
  const float* Wk  = (const float*)d_in[2];
  const float* bk  = (const float*)d_in[3];
  const float* Wq  = (const float*)d_in[4];
  const float* bq  = (const float*)d_in[5];
  const float* Wv  = (const float*)d_in[6];
  const float* bv  = (const float*)d_in[7];
  float* out = (float*)d_out;
  char* ws = (char*)d_ws;

  u16* wqh = (u16*)(ws);
  u16* wql = (u16*)(ws + 256 * 1024);
  u16* wkh = (u16*)(ws + 512 * 1024);
  u16* wkl = (u16*)(ws + 768 * 1024);
  u16* wvh = (u16*)(ws + 1024 * 1024);
  u16* qhp = (u16*)(ws + (size_t)2 * 1024 * 1024);
  u16* qlp = (u16*)(ws + (size_t)6 * 1024 * 1024);
  u16* khp = (u16*)(ws + (size_t)10 * 1024 * 1024);
  u16* klp = (u16*)(ws + (size_t)14 * 1024 * 1024);
  u16* vtp = (u16*)(ws + (size_t)18 * 1024 * 1024);

  prep_w<<<64, 256, 0, stream>>>(Wk, Wq, Wv, wqh, wql, wkh, wkl, wvh);
  qkv_proj<<<256, 256, 0, stream>>>(att, x, wqh, wql, wkh, wkl, wvh,
                                    bq, bk, bv, qhp, qlp, khp, klp, vtp);
  attn<<<256, 256, 0, stream>>>(qhp, qlp, khp, klp, vtp, out);
}

// Round 4
// 262.078 us; speedup vs baseline: 1.1794x; 1.0118x over previous
//
#include <hip/hip_runtime.h>
#include <stdint.h>

typedef unsigned short u16;
typedef __attribute__((ext_vector_type(8))) short bf16x8;
typedef __attribute__((ext_vector_type(4))) float f32x4;

#define T_LEN 2048
#define D_DIM 1024
#define H_DIM 128
// sqrt(128) * log2(e)
#define SCALE_LOG2 16.32223116f

#define EXP2F(x) __builtin_amdgcn_exp2f(x)

__device__ __forceinline__ u16 f2bf(float f) {
  uint32_t u = __float_as_uint(f);
  u += 0x7FFFu + ((u >> 16) & 1u);
  return (u16)(u >> 16);
}
__device__ __forceinline__ float bf2f(u16 h) { return __uint_as_float(((uint32_t)h) << 16); }

__device__ __forceinline__ void gload16(const void* g, void* l) {
  __builtin_amdgcn_global_load_lds(
      (const __attribute__((address_space(1))) uint32_t*)(uintptr_t)g,
      (__attribute__((address_space(3))) uint32_t*)(uint32_t)(uintptr_t)l,
      16, 0, 0);
}

#define VMCNT0() asm volatile("s_waitcnt vmcnt(0)" ::: "memory")
#define VMLG0() asm volatile("s_waitcnt vmcnt(0) lgkmcnt(0)" ::: "memory")
#define BAR() __builtin_amdgcn_s_barrier()
#define PRIO(n) __builtin_amdgcn_s_setprio(n)

#define MFMA(a, b, c) __builtin_amdgcn_mfma_f32_16x16x32_bf16((a), (b), (c), 0, 0, 0)

// ---------------------------------------------------------------------------
// Kernel 0: split W matrices into bf16 hi/lo planes, transposed to wT[h][d].
// ---------------------------------------------------------------------------
__global__ __launch_bounds__(256) void prep_w(
    const float* __restrict__ Wk, const float* __restrict__ Wq, const float* __restrict__ Wv,
    u16* __restrict__ wqh, u16* __restrict__ wql,
    u16* __restrict__ wkh, u16* __restrict__ wkl,
    u16* __restrict__ wvh) {
  __shared__ u16 th[3][128][16];
  __shared__ u16 tl[2][128][16];
  const int i = threadIdx.x;
  const int d0 = blockIdx.x * 16;
  const int dl = i >> 4;
  const int hb = (i & 15) * 8;
  const int d = d0 + dl;
#pragma unroll
  for (int e = 0; e < 8; ++e) {
    int h = hb + e;
    float q = Wq[d * H_DIM + h] * SCALE_LOG2;
    float k = Wk[d * H_DIM + h];
    float v = Wv[d * H_DIM + h];
    u16 qh = f2bf(q); th[0][h][dl] = qh; tl[0][h][dl] = f2bf(q - bf2f(qh));
    u16 kh = f2bf(k); th[1][h][dl] = kh; tl[1][h][dl] = f2bf(k - bf2f(kh));
    th[2][h][dl] = f2bf(v);
  }
  __syncthreads();
  const int h = i >> 1, c = i & 1;
  u16* planes[5] = {wqh, wql, wkh, wkl, wvh};
  const u16* srcs[5] = {&th[0][0][0], &tl[0][0][0], &th[1][0][0], &tl[1][0][0], &th[2][0][0]};
#pragma unroll
  for (int p = 0; p < 5; ++p) {
    bf16x8 v8 = *(const bf16x8*)(srcs[p] + h * 16 + c * 8);
    *(bf16x8*)(planes[p] + h * 1024 + d0 + c * 8) = v8;
  }
}

// ---------------------------------------------------------------------------
// Kernel 1: QKV projection. 512 threads / 8 waves (2 waves/SIMD), 64 rows,
// 2-phase prefetch pipeline (double-buffered LDS). Wave w owns h-tile w.
// ---------------------------------------------------------------------------
#define QBUF 53248  // 52 KB per buffer: A(12K) + W(40K)

__global__ __launch_bounds__(512) void qkv_proj(
    const float* __restrict__ att, const float* __restrict__ x,
    const u16* __restrict__ wqh, const u16* __restrict__ wql,
    const u16* __restrict__ wkh, const u16* __restrict__ wkl,
    const u16* __restrict__ wvh,
    const float* __restrict__ bq, const float* __restrict__ bk, const float* __restrict__ bv,
    u16* __restrict__ qhp, u16* __restrict__ qlp,
    u16* __restrict__ khp, u16* __restrict__ klp,
    u16* __restrict__ vtp) {
  __shared__ __attribute__((aligned(128))) char lds[104 * 1024];

  const int tid = threadIdx.x;
  const int wid = tid >> 6;
  const int ln = tid & 63;
  const int g = ln >> 4;
  const int cl = ln & 15;
  const int t0g = blockIdx.x * 64;

  const f32x4 fz = {0.f, 0.f, 0.f, 0.f};
  f32x4 accq[4], acck[4], accv[4];
#pragma unroll
  for (int s = 0; s < 4; ++s) { accq[s] = fz; acck[s] = fz; accv[s] = fz; }

  // A staging: waves 0-3 handle att (hi+lo), waves 4-7 handle x (hi only)
  const int isA = tid < 256;
  const int at = tid & 255;
  const int arow = at >> 2;   // 0..63
  const int ac = at & 3;      // 8-elem chunk within 32-elem k-slice
  const float* srcp = (isA ? att : x) + (size_t)(t0g + arow) * D_DIM + ac * 8;
  const int aw_off = (isA ? 0 : 8192) + arow * 64 + ((ac ^ ((arow >> 1) & 3)) * 16);

  auto STAGE_W = [&](int b, int ks) {
    char* wt = lds + b * QBUF + 12288;
#pragma unroll
    for (int j = 0; j < 5; ++j) {
      int seg = wid * 5 + j;   // 0..39
      int p = seg >> 3;
      int s = seg & 7;
      int db = s * 1024 + ln * 16;
      int row = db >> 6;
      int c = (db >> 4) & 3;
      int cs = c ^ ((row >> 1) & 3);
      const u16* wp = (p == 0) ? wqh : (p == 1) ? wql : (p == 2) ? wkh : (p == 3) ? wkl : wvh;
      gload16(wp + row * 1024 + ks * 32 + cs * 8, wt + p * 8192 + s * 1024);
    }
  };
  auto CWRITE_A = [&](int b, f32x4 f0, f32x4 f1) {
    bf16x8 vh, vl;
#pragma unroll
    for (int e = 0; e < 4; ++e) {
      u16 h0 = f2bf(f0[e]); vh[e] = (short)h0; vl[e] = (short)f2bf(f0[e] - bf2f(h0));
      u16 h1 = f2bf(f1[e]); vh[e + 4] = (short)h1; vl[e + 4] = (short)f2bf(f1[e] - bf2f(h1));
    }
    char* dst = lds + b * QBUF + aw_off;
    *(bf16x8*)dst = vh;
    if (isA) *(bf16x8*)(dst + 4096) = vl;
  };

  // --- prologue: fill buffer 0 for ks=0 ---
  {
    f32x4 f0 = *(const f32x4*)(srcp);
    f32x4 f1 = *(const f32x4*)(srcp + 4);
    STAGE_W(0, 0);
    CWRITE_A(0, f0, f1);
  }
  VMLG0();
  BAR();

  int cur = 0;
  for (int ks = 0; ks < 32; ++ks) {
    // --- issue next-tile loads early ---
    f32x4 pf0, pf1;
    if (ks < 31) {
      pf0 = *(const f32x4*)(srcp + (ks + 1) * 32);
      pf1 = *(const f32x4*)(srcp + (ks + 1) * 32 + 4);
      STAGE_W(cur ^ 1, ks + 1);
    }
    // --- compute on current buffer ---
    char* base = lds + cur * QBUF;
    char* wt = base + 12288;
    bf16x8 ah[4], al[4], xh[4];
#pragma unroll
    for (int s = 0; s < 4; ++s) {
      int row = s * 16 + cl;
      int byte = row * 64 + ((g ^ ((row >> 1) & 3)) * 16);
      ah[s] = *(const bf16x8*)(base + byte);
      al[s] = *(const bf16x8*)(base + 4096 + byte);
      xh[s] = *(const bf16x8*)(base + 8192 + byte);
    }
    {
      int hrow = wid * 16 + cl;
      int wb = hrow * 64 + ((g ^ ((hrow >> 1) & 3)) * 16);
      bf16x8 bqh_ = *(const bf16x8*)(wt + 0 * 8192 + wb);
      bf16x8 bql_ = *(const bf16x8*)(wt + 1 * 8192 + wb);
      bf16x8 bkh_ = *(const bf16x8*)(wt + 2 * 8192 + wb);
      bf16x8 bkl_ = *(const bf16x8*)(wt + 3 * 8192 + wb);
      bf16x8 bvh_ = *(const bf16x8*)(wt + 4 * 8192 + wb);
      PRIO(1);
#pragma unroll
      for (int s = 0; s < 4; ++s) {
        accq[s] = MFMA(ah[s], bqh_, accq[s]);
        accq[s] = MFMA(al[s], bqh_, accq[s]);
        accq[s] = MFMA(ah[s], bql_, accq[s]);
        acck[s] = MFMA(ah[s], bkh_, acck[s]);
        acck[s] = MFMA(al[s], bkh_, acck[s]);
        acck[s] = MFMA(ah[s], bkl_, acck[s]);
        accv[s] = MFMA(xh[s], bvh_, accv[s]);
      }
      PRIO(0);
    }
    // --- write prefetched A into next buffer (loads had compute time to land) ---
    if (ks < 31) CWRITE_A(cur ^ 1, pf0, pf1);
    VMLG0();
    BAR();
    cur ^= 1;
  }

  // --- epilogue: bias, split q/k, write planes; v -> LDS transpose buffer ---
  char* vbuf = lds;  // 16 KB, all compute done
  {
    int h = wid * 16 + cl;
    float bqv = bq[h] * SCALE_LOG2, bkv = bk[h], bvv = bv[h];
#pragma unroll
    for (int s = 0; s < 4; ++s) {
#pragma unroll
      for (int r = 0; r < 4; ++r) {
        int t = s * 16 + g * 4 + r;
        size_t idx = (size_t)(t0g + t) * H_DIM + h;
        float qv = accq[s][r] + bqv;
        u16 qh_ = f2bf(qv);
        qhp[idx] = qh_;
        qlp[idx] = f2bf(qv - bf2f(qh_));
        float kv = acck[s][r] + bkv;
        u16 kh_ = f2bf(kv);
        khp[idx] = kh_;
        klp[idx] = f2bf(kv - bf2f(kh_));
        float vv = accv[s][r] + bvv;
        int c3 = t >> 3;
        int byte = h * 128 + ((c3 ^ (h & 7)) * 16) + (t & 7) * 2;
        *(u16*)(vbuf + byte) = f2bf(vv);
      }
    }
  }
  __syncthreads();
  // --- vT coalesced writeout (512 threads: h = tid>>2, quarter-row each) ---
  {
    int h = tid >> 2, qtr = tid & 3;
    int b2 = t0g >> 11;
    int tb = t0g & 2047;
    u16* dst = vtp + ((size_t)(b2 * H_DIM + h)) * T_LEN + tb + qtr * 16;
#pragma unroll
    for (int c2 = 0; c2 < 2; ++c2) {
      int c3 = qtr * 2 + c2;
      bf16x8 v8 = *(const bf16x8*)(vbuf + h * 128 + ((c3 ^ (h & 7)) * 16));
      *(bf16x8*)(dst + c2 * 8) = v8;
    }
  }
}

// ---------------------------------------------------------------------------
// Kernel 2: flash attention, 512 threads / 8 waves. Split-KV: waves 0-3 do
// kv [0,1024), waves 4-7 do [1024,2048), each group double-buffered KVBLK=32.
// LDS merge of (m,l,O) at the end. 1-D grid, batch = bid & 7 (XCD locality).
// ---------------------------------------------------------------------------
#define KVB 32
#define GBUF 24576  // per tile: kH 8K + kL 8K + vT 8K

__global__ __launch_bounds__(512) void attn(
    const u16* __restrict__ qhp, const u16* __restrict__ qlp,
    const u16* __restrict__ khp, const u16* __restrict__ klp,
    const u16* __restrict__ vtp,
    float* __restrict__ out) {
  __shared__ __attribute__((aligned(128))) char lds[104 * 1024];

  const int tid = threadIdx.x;
  const int wid = tid >> 6;
  const int w4 = wid & 3;
  const int gb = wid >> 2;       // kv-half group
  const int ln = tid & 63;
  const int g = ln >> 4;
  const int cl = ln & 15;
  const int bid = blockIdx.x;
  const int b_ = bid & 7;        // batch -> XCD
  const int t0 = (bid >> 3) * 64;
  char* gl = lds + gb * 2 * GBUF;          // group's two KV buffers (48 KB)
  char* pW = lds + 96 * 1024 + wid * 1024; // per-wave P: [16][64B]

  auto STAGE = [&](int cb, int tk) {
    char* base = gl + cb * GBUF;
#pragma unroll
    for (int j = 0; j < 6; ++j) {
      int seg = w4 * 6 + j;      // 0..23 within group
      int p = seg >> 3;          // 0:kH 1:kL 2:vT
      int s = seg & 7;
      int db = s * 1024 + ln * 16;
      if (p < 2) {
        int row = db >> 8;       // 0..31
        int c16 = (db >> 4) & 15;
        int cs = c16 ^ (row & 7);
        size_t gidx = (size_t)(b_ * T_LEN + tk + row) * H_DIM + cs * 8;
        gload16((p ? klp : khp) + gidx, base + p * 8192 + s * 1024);
      } else {
        int vrow = db >> 6;      // 0..127
        int c = (db >> 4) & 3;
        int vcs = c ^ (vrow & 3);
        size_t vidx = (size_t)(b_ * H_DIM + vrow) * T_LEN + tk + vcs * 8;
        gload16(vtp + vidx, base + 16384 + s * 1024);
      }
    }
  };

  bf16x8 qh_f[4], ql_f[4];
  {
    size_t qrow = (size_t)(b_ * T_LEN + t0 + w4 * 16 + cl) * H_DIM;
#pragma unroll
    for (int kc = 0; kc < 4; ++kc) {
      qh_f[kc] = *(const bf16x8*)(qhp + qrow + kc * 32 + g * 8);
      ql_f[kc] = *(const bf16x8*)(qlp + qrow + kc * 32 + g * 8);
    }
  }
  const f32x4 fz = {0.f, 0.f, 0.f, 0.f};
  float m_[4] = {-1e30f, -1e30f, -1e30f, -1e30f};
  float l_[4] = {0.f, 0.f, 0.f, 0.f};
  f32x4 o_[8];
#pragma unroll
  for (int ht = 0; ht < 8; ++ht) o_[ht] = fz;

  const int tkbase = gb * 1024;

  // --- prologue ---
  STAGE(0, tkbase);
  VMCNT0();
  BAR();

  int cur = 0;
  for (int kv = 0; kv < 32; ++kv) {
    if (kv < 31) STAGE(cur ^ 1, tkbase + (kv + 1) * KVB);

    char* kH = gl + cur * GBUF;
    char* kL = kH + 8192;
    char* vT = kH + 16384;
    // --- QK^T (split) ---
    f32x4 sc[2] = {fz, fz};
    PRIO(1);
#pragma unroll
    for (int kc = 0; kc < 4; ++kc) {
#pragma unroll
      for (int nt = 0; nt < 2; ++nt) {
        int row = nt * 16 + cl;
        int byte = row * 256 + (((kc * 4 + g) ^ (row & 7)) * 16);
        bf16x8 bh = *(const bf16x8*)(kH + byte);
        bf16x8 bl = *(const bf16x8*)(kL + byte);
        sc[nt] = MFMA(qh_f[kc], bh, sc[nt]);
        sc[nt] = MFMA(ql_f[kc], bh, sc[nt]);
        sc[nt] = MFMA(qh_f[kc], bl, sc[nt]);
      }
    }
    PRIO(0);
    // --- online softmax (exp2 domain) ---
    float sfv[4];
#pragma unroll
    for (int r = 0; r < 4; ++r) {
      float pm = fmaxf(sc[0][r], sc[1][r]);
#pragma unroll
      for (int d = 1; d < 16; d <<= 1) pm = fmaxf(pm, __shfl_xor(pm, d));
      float mn = fmaxf(m_[r], pm);
      float sf = EXP2F(m_[r] - mn);
      m_[r] = mn; sfv[r] = sf;
      float ps = 0.f;
      int prow = g * 4 + r;
#pragma unroll
      for (int nt = 0; nt < 2; ++nt) {
        float p = EXP2F(sc[nt][r] - mn);
        ps += p;
        int c3 = nt * 2 + (cl >> 3);
        int byte = prow * 64 + ((c3 ^ (prow & 3)) * 16) + (cl & 7) * 2;
        *(u16*)(pW + byte) = f2bf(p);
      }
#pragma unroll
      for (int d = 1; d < 16; d <<= 1) ps += __shfl_xor(ps, d);
      l_[r] = l_[r] * sf + ps;
    }
#pragma unroll
    for (int ht = 0; ht < 8; ++ht) {
      o_[ht][0] *= sfv[0]; o_[ht][1] *= sfv[1]; o_[ht][2] *= sfv[2]; o_[ht][3] *= sfv[3];
    }
    // --- PV ---
    {
      int pbyte = cl * 64 + ((g ^ (cl & 3)) * 16);
      bf16x8 ap = *(const bf16x8*)(pW + pbyte);
      PRIO(1);
#pragma unroll
      for (int ht = 0; ht < 8; ++ht) {
        int vrow = ht * 16 + cl;
        int vbyte = vrow * 64 + ((g ^ (vrow & 3)) * 16);
        bf16x8 bv_ = *(const bf16x8*)(vT + vbyte);
        o_[ht] = MFMA(ap, bv_, o_[ht]);
      }
      PRIO(0);
    }
    VMCNT0();
    BAR();
    cur ^= 1;
  }

  // --- split-KV merge: group B publishes (O, m, l); group A combines ---
  if (gb == 1) {
    char* ob = lds + w4 * 8192 + ln * 128;
#pragma unroll
    for (int ht = 0; ht < 8; ++ht) *(f32x4*)(ob + ht * 16) = o_[ht];
    f32x4 mv = {m_[0], m_[1], m_[2], m_[3]};
    f32x4 lv = {l_[0], l_[1], l_[2], l_[3]};
    char* mb = lds + 32768 + w4 * 2048 + ln * 32;
    *(f32x4*)mb = mv;
    *(f32x4*)(mb + 16) = lv;
  }
  __syncthreads();
  if (gb == 0) {
    char* ob = lds + w4 * 8192 + ln * 128;
    char* mb = lds + 32768 + w4 * 2048 + ln * 32;
    f32x4 mB = *(const f32x4*)mb;
    f32x4 lB = *(const f32x4*)(mb + 16);
    float sA[4], sB[4];
#pragma unroll
    for (int r = 0; r < 4; ++r) {
      float m = fmaxf(m_[r], mB[r]);
      float fa = EXP2F(m_[r] - m);
      float fb = EXP2F(mB[r] - m);
      float inv = 1.f / (l_[r] * fa + lB[r] * fb);
      sA[r] = fa * inv;
      sB[r] = fb * inv;
    }
    size_t obase = (size_t)(b_ * T_LEN + t0 + w4 * 16) * H_DIM;
#pragma unroll
    for (int ht = 0; ht < 8; ++ht) {
      f32x4 oB = *(const f32x4*)(ob + ht * 16);
#pragma unroll
      for (int r = 0; r < 4; ++r) {
        out[obase + (size_t)(g * 4 + r) * H_DIM + ht * 16 + cl] =
            o_[ht][r] * sA[r] + oB[r] * sB[r];
      }
    }
  }
}

// ---------------------------------------------------------------------------
extern "C" void kernel_launch(void* const* d_in, const int* in_sizes, int n_in,
                              void* d_out, int out_size, void* d_ws, size_t ws_size,
                              hipStream_t stream) {
  const float* x   = (const float*)d_in[0];
  const float* att = (const float*)d_in[1];
  const float* Wk  = (const float*)d_in[2];
  const float* bk  = (const float*)d_in[3];
  const float* Wq  = (const float*)d_in[4];
  const float* bq  = (const float*)d_in[5];
  const float* Wv  = (const float*)d_in[6];
  const float* bv  = (const float*)d_in[7];
  float* out = (float*)d_out;
  char* ws = (char*)d_ws;

  u16* wqh = (u16*)(ws);
  u16* wql = (u16*)(ws + 256 * 1024);
  u16* wkh = (u16*)(ws + 512 * 1024);
  u16* wkl = (u16*)(ws + 768 * 1024);
  u16* wvh = (u16*)(ws + 1024 * 1024);
  u16* qhp = (u16*)(ws + (size_t)2 * 1024 * 1024);
  u16* qlp = (u16*)(ws + (size_t)6 * 1024 * 1024);
  u16* khp = (u16*)(ws + (size_t)10 * 1024 * 1024);
  u16* klp = (u16*)(ws + (size_t)14 * 1024 * 1024);
  u16* vtp = (u16*)(ws + (size_t)18 * 1024 * 1024);

  prep_w<<<64, 256, 0, stream>>>(Wk, Wq, Wv, wqh, wql, wkh, wkl, wvh);
  qkv_proj<<<256, 512, 0, stream>>>(att, x, wqh, wql, wkh, wkl, wvh,
                                    bq, bk, bv, qhp, qlp, khp, klp, vtp);
  attn<<<256, 512, 0, stream>>>(qhp, qlp, khp, klp, vtp, out);
}